// Round 1
// baseline (4269.110 us; speedup 1.0000x reference)
//
#include <hip/hip_runtime.h>

#define N_NODES 50000
#define N_EDGES 800000
#define HID 128
#define F_IN 11
#define N_ACT 6
#define BN 64

// ---------------- degree / normalization ----------------

__global__ __launch_bounds__(256) void k_count_deg(const int* __restrict__ edst,
                                                   int* __restrict__ cnt, int E) {
  int e = blockIdx.x * 256 + threadIdx.x;
  if (e < E) atomicAdd(&cnt[edst[e]], 1);
}

__global__ __launch_bounds__(256) void k_dinv(const int* __restrict__ cnt,
                                              float* __restrict__ dinv, int n) {
  int i = blockIdx.x * 256 + threadIdx.x;
  if (i < n) dinv[i] = rsqrtf((float)cnt[i] + 1.0f);
}

// ---------------- GEMMs (fp32, vector ALU — no fp32 MFMA on CDNA4) ----------------

// X[n,11] @ W[11,128] -> H[n,128]; 2 nodes per 256-thread block, W in LDS.
__global__ __launch_bounds__(256) void k_gemm_in(const float* __restrict__ X,
                                                 const float* __restrict__ W,
                                                 float* __restrict__ H, int n) {
  __shared__ float Ws[F_IN * HID];
  int tid = threadIdx.x;
  for (int i = tid; i < F_IN * HID; i += 256) Ws[i] = W[i];
  __syncthreads();
  int node = blockIdx.x * 2 + (tid >> 7);
  int j = tid & 127;
  if (node >= n) return;
  const float* xr = X + (size_t)node * F_IN;
  float a = 0.f;
#pragma unroll
  for (int k = 0; k < F_IN; ++k) a = fmaf(xr[k], Ws[k * HID + j], a);
  H[(size_t)node * HID + j] = a;
}

// X[n,128] @ W[128,128] -> H[n,128]. Block: 256 threads, 64 nodes.
// W (64KB) + X-tile (33KB) in LDS; thread computes 4 nodes x 8 cols in registers.
__global__ __launch_bounds__(256) void k_gemm128(const float* __restrict__ X,
                                                 const float* __restrict__ W,
                                                 float* __restrict__ H, int n) {
  __shared__ float Ws[128 * 128];
  __shared__ float Xs[BN][129];  // +1 pad: node-stride bank spread
  int tid = threadIdx.x;
  {
    const float4* Wv = (const float4*)W;
    float4* Wsv = (float4*)Ws;
#pragma unroll
    for (int i = 0; i < 16; ++i) Wsv[tid + i * 256] = Wv[tid + i * 256];
  }
  int n0 = blockIdx.x * BN;
  for (int i = tid; i < BN * 32; i += 256) {
    int r = i >> 5, c4 = i & 31;
    float4 v = make_float4(0.f, 0.f, 0.f, 0.f);
    int node = n0 + r;
    if (node < n) v = ((const float4*)(X + (size_t)node * 128))[c4];
    Xs[r][c4 * 4 + 0] = v.x;
    Xs[r][c4 * 4 + 1] = v.y;
    Xs[r][c4 * 4 + 2] = v.z;
    Xs[r][c4 * 4 + 3] = v.w;
  }
  __syncthreads();
  int tc = tid & 15, tr = tid >> 4;  // 16 col-groups x 16 node-groups
  float acc[4][8];
#pragma unroll
  for (int i = 0; i < 4; ++i)
#pragma unroll
    for (int j = 0; j < 8; ++j) acc[i][j] = 0.f;
  for (int k = 0; k < 128; ++k) {
    float xa[4];
#pragma unroll
    for (int i = 0; i < 4; ++i) xa[i] = Xs[tr * 4 + i][k];
    const float* wr = &Ws[k * 128 + tc * 8];
#pragma unroll
    for (int j = 0; j < 8; ++j) {
      float wb = wr[j];
#pragma unroll
      for (int i = 0; i < 4; ++i) acc[i][j] = fmaf(xa[i], wb, acc[i][j]);
    }
  }
#pragma unroll
  for (int i = 0; i < 4; ++i) {
    int node = n0 + tr * 4 + i;
    if (node < n) {
      float4* outp = (float4*)(H + (size_t)node * 128 + tc * 8);
      outp[0] = make_float4(acc[i][0], acc[i][1], acc[i][2], acc[i][3]);
      outp[1] = make_float4(acc[i][4], acc[i][5], acc[i][6], acc[i][7]);
    }
  }
}

// ---------------- GCN aggregation ----------------

// agg = h * dinv^2 (self-loop term), elementwise float4
__global__ __launch_bounds__(256) void k_init_agg(const float* __restrict__ h,
                                                  const float* __restrict__ dinv,
                                                  float* __restrict__ agg, int n) {
  int i = blockIdx.x * 256 + threadIdx.x;  // float4 index
  if (i >= n * 32) return;
  int node = i >> 5;
  float d = dinv[node];
  float s = d * d;
  float4 v = ((const float4*)h)[i];
  v.x *= s; v.y *= s; v.z *= s; v.w *= s;
  ((float4*)agg)[i] = v;
}

// 32 lanes per edge; each lane: float4 gather of h[src], 4 atomic adds to agg[dst]
__global__ __launch_bounds__(256) void k_edge(const float* __restrict__ h,
                                              const float* __restrict__ dinv,
                                              const int* __restrict__ esrc,
                                              const int* __restrict__ edst,
                                              float* __restrict__ agg, int E) {
  int gid = blockIdx.x * 256 + threadIdx.x;
  int e = gid >> 5;
  int lane = gid & 31;
  if (e >= E) return;
  int s = esrc[e], d = edst[e];
  float w = dinv[s] * dinv[d];
  float4 v = ((const float4*)(h + (size_t)s * 128))[lane];
  float* ap = agg + (size_t)d * 128 + lane * 4;
  atomicAdd(ap + 0, v.x * w);
  atomicAdd(ap + 1, v.y * w);
  atomicAdd(ap + 2, v.z * w);
  atomicAdd(ap + 3, v.w * w);
}

// out = relu(agg + b), float4
__global__ __launch_bounds__(256) void k_final(const float* __restrict__ agg,
                                               const float* __restrict__ b,
                                               float* __restrict__ out, int n) {
  int i = blockIdx.x * 256 + threadIdx.x;  // float4 index
  if (i >= n * 32) return;
  float4 bb = ((const float4*)b)[i & 31];
  float4 v = ((const float4*)agg)[i];
  v.x = fmaxf(v.x + bb.x, 0.f);
  v.y = fmaxf(v.y + bb.y, 0.f);
  v.z = fmaxf(v.z + bb.z, 0.f);
  v.w = fmaxf(v.w + bb.w, 0.f);
  ((float4*)out)[i] = v;
}

// ---------------- pooling + dueling head ----------------

__global__ __launch_bounds__(256) void k_colsum(const float* __restrict__ h,
                                                float* __restrict__ gsum, int n) {
  __shared__ float red[256];
  int t = threadIdx.x;
  int f = t & 127;
  int half = t >> 7;
  float s = 0.f;
  for (int node = blockIdx.x * 2 + half; node < n; node += gridDim.x * 2)
    s += h[(size_t)node * HID + f];
  red[t] = s;
  __syncthreads();
  if (t < 128) atomicAdd(&gsum[f], red[t] + red[t + 128]);
}

__global__ __launch_bounds__(128) void k_head(const float* __restrict__ gsum,
    const float* __restrict__ Wv1, const float* __restrict__ bv1,
    const float* __restrict__ Wv2, const float* __restrict__ bv2,
    const float* __restrict__ Wa1, const float* __restrict__ ba1,
    const float* __restrict__ Wa2, const float* __restrict__ ba2,
    float* __restrict__ out) {
  __shared__ float gs[HID], ha[HID], red[2], advs[N_ACT], vsh;
  int t = threadIdx.x;
  gs[t] = gsum[t] * (1.0f / (float)N_NODES);
  __syncthreads();
  float av = bv1[t], aa = ba1[t];
  for (int k = 0; k < HID; ++k) {
    float gk = gs[k];
    av = fmaf(gk, Wv1[k * HID + t], av);
    aa = fmaf(gk, Wa1[k * HID + t], aa);
  }
  float hv = fmaxf(av, 0.f);
  ha[t] = fmaxf(aa, 0.f);
  float pv = hv * Wv2[t];
#pragma unroll
  for (int o = 32; o > 0; o >>= 1) pv += __shfl_down(pv, o);
  if ((t & 63) == 0) red[t >> 6] = pv;
  __syncthreads();
  if (t == 0) vsh = red[0] + red[1] + bv2[0];
  if (t < N_ACT) {
    float adv = ba2[t];
    for (int j = 0; j < HID; ++j) adv = fmaf(ha[j], Wa2[j * N_ACT + t], adv);
    advs[t] = adv;
  }
  __syncthreads();
  if (t < N_ACT) {
    float m = 0.f;
#pragma unroll
    for (int a = 0; a < N_ACT; ++a) m += advs[a];
    m *= (1.0f / N_ACT);
    out[t] = vsh + advs[t] - m;
  }
}

// ---------------- launch ----------------

extern "C" void kernel_launch(void* const* d_in, const int* in_sizes, int n_in,
                              void* d_out, int out_size, void* d_ws, size_t ws_size,
                              hipStream_t stream) {
  const float* x   = (const float*)d_in[0];
  const int*   ei  = (const int*)d_in[1];
  const float* W1  = (const float*)d_in[2];
  const float* b1  = (const float*)d_in[3];
  const float* W2  = (const float*)d_in[4];
  const float* b2  = (const float*)d_in[5];
  const float* W3  = (const float*)d_in[6];
  const float* b3  = (const float*)d_in[7];
  const float* Wv1 = (const float*)d_in[8];
  const float* bv1 = (const float*)d_in[9];
  const float* Wv2 = (const float*)d_in[10];
  const float* bv2 = (const float*)d_in[11];
  const float* Wa1 = (const float*)d_in[12];
  const float* ba1 = (const float*)d_in[13];
  const float* Wa2 = (const float*)d_in[14];
  const float* ba2 = (const float*)d_in[15];
  float* out = (float*)d_out;

  const int N = in_sizes[0] / F_IN;     // 50000
  const int E = in_sizes[1] / 2;        // 800000
  const int* esrc = ei;
  const int* edst = ei + E;

  // workspace layout (offsets in floats, 256-aligned)
  char* ws = (char*)d_ws;
  int*   cnt  = (int*)ws;                                   // 51200 ints
  float* dinv = (float*)(ws + 51200 * 4);                   // 51200 f
  float* B1   = (float*)(ws + 102400 * 4);                  // N*HID
  float* B2   = B1 + (size_t)N * HID;
  float* B3   = B2 + (size_t)N * HID;
  float* gsum = B3 + (size_t)N * HID;                       // 128 f

  hipMemsetAsync(cnt, 0, N * sizeof(int), stream);
  hipMemsetAsync(gsum, 0, HID * sizeof(float), stream);

  k_count_deg<<<(E + 255) / 256, 256, 0, stream>>>(edst, cnt, E);
  k_dinv<<<(N + 255) / 256, 256, 0, stream>>>(cnt, dinv, N);

  int gElem4 = (N * 32 + 255) / 256;   // float4 elementwise grids
  int gEdge  = (E * 32 + 255) / 256;
  int gGemm  = (N + BN - 1) / BN;

  // layer 1: x (11 cols)
  k_gemm_in<<<(N + 1) / 2, 256, 0, stream>>>(x, W1, B1, N);
  k_init_agg<<<gElem4, 256, 0, stream>>>(B1, dinv, B2, N);
  k_edge<<<gEdge, 256, 0, stream>>>(B1, dinv, esrc, edst, B2, E);
  k_final<<<gElem4, 256, 0, stream>>>(B2, b1, B3, N);

  // layer 2
  k_gemm128<<<gGemm, 256, 0, stream>>>(B3, W2, B1, N);
  k_init_agg<<<gElem4, 256, 0, stream>>>(B1, dinv, B2, N);
  k_edge<<<gEdge, 256, 0, stream>>>(B1, dinv, esrc, edst, B2, E);
  k_final<<<gElem4, 256, 0, stream>>>(B2, b2, B3, N);

  // layer 3
  k_gemm128<<<gGemm, 256, 0, stream>>>(B3, W3, B1, N);
  k_init_agg<<<gElem4, 256, 0, stream>>>(B1, dinv, B2, N);
  k_edge<<<gEdge, 256, 0, stream>>>(B1, dinv, esrc, edst, B2, E);
  k_final<<<gElem4, 256, 0, stream>>>(B2, b3, B3, N);

  // pool + head
  k_colsum<<<512, 256, 0, stream>>>(B3, gsum, N);
  k_head<<<1, 128, 0, stream>>>(gsum, Wv1, bv1, Wv2, bv2, Wa1, ba1, Wa2, ba2, out);
}

// Round 2
// 415.705 us; speedup vs baseline: 10.2696x; 10.2696x over previous
//
#include <hip/hip_runtime.h>

#define HID 128
#define F_IN 11
#define FP 16      // x padded to 16 cols for aligned 64B gathers
#define N_ACT 6
#define BN 64

// ---------------- degree / normalization ----------------

__global__ __launch_bounds__(256) void k_count_deg(const int* __restrict__ edst,
                                                   int* __restrict__ cnt, int E) {
  int e = blockIdx.x * 256 + threadIdx.x;
  if (e < E) atomicAdd(&cnt[edst[e]], 1);
}

__global__ __launch_bounds__(256) void k_dinv(const int* __restrict__ cnt,
                                              float* __restrict__ dinv, int n) {
  int i = blockIdx.x * 256 + threadIdx.x;
  if (i < n) dinv[i] = rsqrtf((float)cnt[i] + 1.0f);
}

// ---------------- CSR build: scan + fill ----------------

__global__ __launch_bounds__(256) void k_scan1(const int* __restrict__ cnt,
                                               int* __restrict__ bsum, int n) {
  __shared__ int sh[256];
  int t = threadIdx.x, i = blockIdx.x * 256 + t;
  sh[t] = (i < n) ? cnt[i] : 0;
  __syncthreads();
  for (int off = 128; off > 0; off >>= 1) {
    if (t < off) sh[t] += sh[t + off];
    __syncthreads();
  }
  if (t == 0) bsum[blockIdx.x] = sh[0];
}

__global__ __launch_bounds__(256) void k_scan2(const int* __restrict__ bsum,
                                               int* __restrict__ boff, int nb) {
  __shared__ int sh[256];
  int t = threadIdx.x;
  int v = (t < nb) ? bsum[t] : 0;
  sh[t] = v;
  __syncthreads();
  for (int off = 1; off < 256; off <<= 1) {
    int x = (t >= off) ? sh[t - off] : 0;
    __syncthreads();
    sh[t] += x;
    __syncthreads();
  }
  if (t < nb) boff[t] = sh[t] - v;
}

__global__ __launch_bounds__(256) void k_scan3(const int* __restrict__ cnt,
                                               const int* __restrict__ boff,
                                               int* __restrict__ rowptr,
                                               int* __restrict__ cur, int n) {
  __shared__ int sh[256];
  int t = threadIdx.x, i = blockIdx.x * 256 + t;
  int v = (i < n) ? cnt[i] : 0;
  sh[t] = v;
  __syncthreads();
  for (int off = 1; off < 256; off <<= 1) {
    int x = (t >= off) ? sh[t - off] : 0;
    __syncthreads();
    sh[t] += x;
    __syncthreads();
  }
  int excl = boff[blockIdx.x] + sh[t] - v;
  if (i < n) {
    rowptr[i] = excl;
    cur[i] = excl;
    if (i == n - 1) rowptr[n] = excl + v;
  }
}

// col+weight packed: .x = src node, .y = bitcast(dinv[src]*dinv[dst])
__global__ __launch_bounds__(256) void k_fill(const int* __restrict__ esrc,
                                              const int* __restrict__ edst,
                                              const float* __restrict__ dinv,
                                              int* __restrict__ cur,
                                              int2* __restrict__ csw, int E) {
  int e = blockIdx.x * 256 + threadIdx.x;
  if (e >= E) return;
  int s = esrc[e], d = edst[e];
  float w = dinv[s] * dinv[d];
  int p = atomicAdd(&cur[d], 1);
  csw[p] = make_int2(s, __float_as_int(w));
}

// ---------------- pad x to 16 cols ----------------

__global__ __launch_bounds__(256) void k_pad(const float* __restrict__ x,
                                             float* __restrict__ xp, int n) {
  int i = blockIdx.x * 256 + threadIdx.x;
  if (i >= n * FP) return;
  int node = i >> 4, c = i & 15;
  xp[i] = (c < F_IN) ? x[(size_t)node * F_IN + c] : 0.f;
}

// ---------------- gather aggregation (no atomics) ----------------

// A1 = Â xp  (16-wide). 16 lanes per node, 1 float each.
__global__ __launch_bounds__(256) void k_gather16(const float* __restrict__ xp,
                                                  const float* __restrict__ dinv,
                                                  const int* __restrict__ rowptr,
                                                  const int2* __restrict__ csw,
                                                  float* __restrict__ A, int n) {
  int t = threadIdx.x;
  int node = blockIdx.x * 16 + (t >> 4);
  int c = t & 15;
  if (node >= n) return;
  float dd = dinv[node];
  float acc = xp[(size_t)node * FP + c] * dd * dd;
  int j = rowptr[node], jend = rowptr[node + 1];
  for (; j + 1 < jend; j += 2) {
    int2 a = csw[j], b = csw[j + 1];
    acc = fmaf(xp[(size_t)a.x * FP + c], __int_as_float(a.y), acc);
    acc = fmaf(xp[(size_t)b.x * FP + c], __int_as_float(b.y), acc);
  }
  if (j < jend) {
    int2 a = csw[j];
    acc = fmaf(xp[(size_t)a.x * FP + c], __int_as_float(a.y), acc);
  }
  A[(size_t)node * FP + c] = acc;
}

// A = Â h  (128-wide). One wave (64 lanes) per node, float2 per lane.
__global__ __launch_bounds__(256) void k_gather128(const float* __restrict__ h,
                                                   const float* __restrict__ dinv,
                                                   const int* __restrict__ rowptr,
                                                   const int2* __restrict__ csw,
                                                   float* __restrict__ A, int n) {
  int t = threadIdx.x;
  int node = blockIdx.x * 4 + (t >> 6);
  int l = t & 63;
  if (node >= n) return;
  const float2* h2 = (const float2*)h;
  float dd = dinv[node];
  float2 acc = h2[(size_t)node * 64 + l];
  acc.x *= dd * dd;
  acc.y *= dd * dd;
  int j = rowptr[node], jend = rowptr[node + 1];
  for (; j + 1 < jend; j += 2) {
    int2 a = csw[j], b = csw[j + 1];
    float wa = __int_as_float(a.y), wb = __int_as_float(b.y);
    float2 va = h2[(size_t)a.x * 64 + l];
    float2 vb = h2[(size_t)b.x * 64 + l];
    acc.x = fmaf(va.x, wa, acc.x);
    acc.y = fmaf(va.y, wa, acc.y);
    acc.x = fmaf(vb.x, wb, acc.x);
    acc.y = fmaf(vb.y, wb, acc.y);
  }
  if (j < jend) {
    int2 a = csw[j];
    float wa = __int_as_float(a.y);
    float2 va = h2[(size_t)a.x * 64 + l];
    acc.x = fmaf(va.x, wa, acc.x);
    acc.y = fmaf(va.y, wa, acc.y);
  }
  ((float2*)A)[(size_t)node * 64 + l] = acc;
}

// ---------------- GEMMs (fp32 vector ALU) with bias+relu epilogue ----------------

// A[n,16 (11 used)] @ W[11,128] -> relu(+b) -> H[n,128]; 2 nodes per block.
__global__ __launch_bounds__(256) void k_gemm_in(const float* __restrict__ X,
                                                 const float* __restrict__ W,
                                                 const float* __restrict__ b,
                                                 float* __restrict__ H, int n) {
  __shared__ float Ws[F_IN * HID];
  int tid = threadIdx.x;
  for (int i = tid; i < F_IN * HID; i += 256) Ws[i] = W[i];
  __syncthreads();
  int node = blockIdx.x * 2 + (tid >> 7);
  int j = tid & 127;
  if (node >= n) return;
  const float* xr = X + (size_t)node * FP;
  float a = 0.f;
#pragma unroll
  for (int k = 0; k < F_IN; ++k) a = fmaf(xr[k], Ws[k * HID + j], a);
  H[(size_t)node * HID + j] = fmaxf(a + b[j], 0.f);
}

// A[n,128] @ W[128,128] -> relu(+b) -> H[n,128]. 64 nodes/block, 4x8 regs/thread.
__global__ __launch_bounds__(256) void k_gemm128(const float* __restrict__ X,
                                                 const float* __restrict__ W,
                                                 const float* __restrict__ b,
                                                 float* __restrict__ H, int n) {
  __shared__ float Ws[128 * 128];
  __shared__ float Xs[BN][129];
  int tid = threadIdx.x;
  {
    const float4* Wv = (const float4*)W;
    float4* Wsv = (float4*)Ws;
#pragma unroll
    for (int i = 0; i < 16; ++i) Wsv[tid + i * 256] = Wv[tid + i * 256];
  }
  int n0 = blockIdx.x * BN;
  for (int i = tid; i < BN * 32; i += 256) {
    int r = i >> 5, c4 = i & 31;
    float4 v = make_float4(0.f, 0.f, 0.f, 0.f);
    int node = n0 + r;
    if (node < n) v = ((const float4*)(X + (size_t)node * 128))[c4];
    Xs[r][c4 * 4 + 0] = v.x;
    Xs[r][c4 * 4 + 1] = v.y;
    Xs[r][c4 * 4 + 2] = v.z;
    Xs[r][c4 * 4 + 3] = v.w;
  }
  __syncthreads();
  int tc = tid & 15, tr = tid >> 4;
  float acc[4][8];
#pragma unroll
  for (int i = 0; i < 4; ++i)
#pragma unroll
    for (int j = 0; j < 8; ++j) acc[i][j] = 0.f;
  for (int k = 0; k < 128; ++k) {
    float xa[4];
#pragma unroll
    for (int i = 0; i < 4; ++i) xa[i] = Xs[tr * 4 + i][k];
    const float* wr = &Ws[k * 128 + tc * 8];
#pragma unroll
    for (int j = 0; j < 8; ++j) {
      float wb = wr[j];
#pragma unroll
      for (int i = 0; i < 4; ++i) acc[i][j] = fmaf(xa[i], wb, acc[i][j]);
    }
  }
  float bb[8];
#pragma unroll
  for (int j = 0; j < 8; ++j) bb[j] = b[tc * 8 + j];
#pragma unroll
  for (int i = 0; i < 4; ++i) {
    int node = n0 + tr * 4 + i;
    if (node < n) {
      float4* outp = (float4*)(H + (size_t)node * 128 + tc * 8);
      outp[0] = make_float4(fmaxf(acc[i][0] + bb[0], 0.f), fmaxf(acc[i][1] + bb[1], 0.f),
                            fmaxf(acc[i][2] + bb[2], 0.f), fmaxf(acc[i][3] + bb[3], 0.f));
      outp[1] = make_float4(fmaxf(acc[i][4] + bb[4], 0.f), fmaxf(acc[i][5] + bb[5], 0.f),
                            fmaxf(acc[i][6] + bb[6], 0.f), fmaxf(acc[i][7] + bb[7], 0.f));
    }
  }
}

// ---------------- pooling + dueling head ----------------

__global__ __launch_bounds__(256) void k_colsum(const float* __restrict__ h,
                                                float* __restrict__ gsum, int n) {
  __shared__ float red[256];
  int t = threadIdx.x;
  int f = t & 127;
  int half = t >> 7;
  float s = 0.f;
  for (int node = blockIdx.x * 2 + half; node < n; node += gridDim.x * 2)
    s += h[(size_t)node * HID + f];
  red[t] = s;
  __syncthreads();
  if (t < 128) atomicAdd(&gsum[f], red[t] + red[t + 128]);
}

__global__ __launch_bounds__(128) void k_head(const float* __restrict__ gsum,
    const float* __restrict__ Wv1, const float* __restrict__ bv1,
    const float* __restrict__ Wv2, const float* __restrict__ bv2,
    const float* __restrict__ Wa1, const float* __restrict__ ba1,
    const float* __restrict__ Wa2, const float* __restrict__ ba2,
    float* __restrict__ out, int n) {
  __shared__ float gs[HID], ha[HID], red[2], advs[N_ACT], vsh;
  int t = threadIdx.x;
  gs[t] = gsum[t] * (1.0f / (float)n);
  __syncthreads();
  float av = bv1[t], aa = ba1[t];
  for (int k = 0; k < HID; ++k) {
    float gk = gs[k];
    av = fmaf(gk, Wv1[k * HID + t], av);
    aa = fmaf(gk, Wa1[k * HID + t], aa);
  }
  float hv = fmaxf(av, 0.f);
  ha[t] = fmaxf(aa, 0.f);
  float pv = hv * Wv2[t];
#pragma unroll
  for (int o = 32; o > 0; o >>= 1) pv += __shfl_down(pv, o);
  if ((t & 63) == 0) red[t >> 6] = pv;
  __syncthreads();
  if (t == 0) vsh = red[0] + red[1] + bv2[0];
  if (t < N_ACT) {
    float adv = ba2[t];
    for (int j = 0; j < HID; ++j) adv = fmaf(ha[j], Wa2[j * N_ACT + t], adv);
    advs[t] = adv;
  }
  __syncthreads();
  if (t < N_ACT) {
    float m = 0.f;
#pragma unroll
    for (int a = 0; a < N_ACT; ++a) m += advs[a];
    m *= (1.0f / N_ACT);
    out[t] = vsh + advs[t] - m;
  }
}

// ---------------- launch ----------------

extern "C" void kernel_launch(void* const* d_in, const int* in_sizes, int n_in,
                              void* d_out, int out_size, void* d_ws, size_t ws_size,
                              hipStream_t stream) {
  const float* x   = (const float*)d_in[0];
  const int*   ei  = (const int*)d_in[1];
  const float* W1  = (const float*)d_in[2];
  const float* b1  = (const float*)d_in[3];
  const float* W2  = (const float*)d_in[4];
  const float* b2  = (const float*)d_in[5];
  const float* W3  = (const float*)d_in[6];
  const float* b3  = (const float*)d_in[7];
  const float* Wv1 = (const float*)d_in[8];
  const float* bv1 = (const float*)d_in[9];
  const float* Wv2 = (const float*)d_in[10];
  const float* bv2 = (const float*)d_in[11];
  const float* Wa1 = (const float*)d_in[12];
  const float* ba1 = (const float*)d_in[13];
  const float* Wa2 = (const float*)d_in[14];
  const float* ba2 = (const float*)d_in[15];
  float* out = (float*)d_out;

  const int N = in_sizes[0] / F_IN;   // 50000
  const int E = in_sizes[1] / 2;      // 800000
  const int* esrc = ei;
  const int* edst = ei + E;
  const int nb = (N + 255) / 256;     // scan blocks

  // workspace layout (1KB-aligned chunks)
  char* p = (char*)d_ws;
  auto alloc = [&](size_t bytes) {
    void* r = (void*)p;
    p += (bytes + 1023) & ~(size_t)1023;
    return r;
  };
  int*   cnt    = (int*)alloc((size_t)N * 4);
  float* dinv   = (float*)alloc((size_t)N * 4);
  int*   rowptr = (int*)alloc((size_t)(N + 1) * 4);
  int*   cur    = (int*)alloc((size_t)N * 4);
  int*   bsum   = (int*)alloc(256 * 4);
  int*   boff   = (int*)alloc(256 * 4);
  int2*  csw    = (int2*)alloc((size_t)E * 8);
  float* xp     = (float*)alloc((size_t)N * FP * 4);
  float* A      = (float*)alloc((size_t)N * HID * 4);
  float* H      = (float*)alloc((size_t)N * HID * 4);
  float* gsum   = (float*)alloc(HID * 4);

  hipMemsetAsync(cnt, 0, (size_t)N * 4, stream);
  hipMemsetAsync(gsum, 0, HID * 4, stream);

  // CSR build
  k_count_deg<<<(E + 255) / 256, 256, 0, stream>>>(edst, cnt, E);
  k_dinv<<<(N + 255) / 256, 256, 0, stream>>>(cnt, dinv, N);
  k_pad<<<(N * FP + 255) / 256, 256, 0, stream>>>(x, xp, N);
  k_scan1<<<nb, 256, 0, stream>>>(cnt, bsum, N);
  k_scan2<<<1, 256, 0, stream>>>(bsum, boff, nb);
  k_scan3<<<nb, 256, 0, stream>>>(cnt, boff, rowptr, cur, N);
  k_fill<<<(E + 255) / 256, 256, 0, stream>>>(esrc, edst, dinv, cur, csw, E);

  // layer 1: aggregate x (16-wide) then GEMM 11->128
  k_gather16<<<(N + 15) / 16, 256, 0, stream>>>(xp, dinv, rowptr, csw, A, N);
  k_gemm_in<<<(N + 1) / 2, 256, 0, stream>>>(A, W1, b1, H, N);

  // layer 2
  k_gather128<<<(N + 3) / 4, 256, 0, stream>>>(H, dinv, rowptr, csw, A, N);
  k_gemm128<<<(N + BN - 1) / BN, 256, 0, stream>>>(A, W2, b2, H, N);

  // layer 3
  k_gather128<<<(N + 3) / 4, 256, 0, stream>>>(H, dinv, rowptr, csw, A, N);
  k_gemm128<<<(N + BN - 1) / BN, 256, 0, stream>>>(A, W3, b3, H, N);

  // pool + head
  k_colsum<<<512, 256, 0, stream>>>(H, gsum, N);
  k_head<<<1, 128, 0, stream>>>(gsum, Wv1, bv1, Wv2, bv2, Wa1, ba1, Wa2, ba2, out, N);
}

// Round 3
// 314.842 us; speedup vs baseline: 13.5595x; 1.3204x over previous
//
#include <hip/hip_runtime.h>

#define HID 128
#define F_IN 11
#define FP 16
#define N_ACT 6

typedef __bf16 bf16;
typedef __bf16 v8bf __attribute__((ext_vector_type(8)));
typedef float f32x4 __attribute__((ext_vector_type(4)));

__device__ inline float lo16(unsigned u) { return __uint_as_float(u << 16); }
__device__ inline float hi16(unsigned u) { return __uint_as_float(u & 0xffff0000u); }

// ---------------- degree / normalization ----------------

__global__ __launch_bounds__(256) void k_count_deg(const int* __restrict__ edst,
                                                   int* __restrict__ cnt, int E) {
  int e = blockIdx.x * 256 + threadIdx.x;
  if (e < E) atomicAdd(&cnt[edst[e]], 1);
}

__global__ __launch_bounds__(256) void k_dinv(const int* __restrict__ cnt,
                                              float* __restrict__ dinv, int n) {
  int i = blockIdx.x * 256 + threadIdx.x;
  if (i < n) dinv[i] = rsqrtf((float)cnt[i] + 1.0f);
}

// xs = x * dinv (bf16, padded to 16 cols)
__global__ __launch_bounds__(256) void k_pad(const float* __restrict__ x,
                                             const float* __restrict__ dinv,
                                             bf16* __restrict__ xs, int n) {
  int i = blockIdx.x * 256 + threadIdx.x;
  if (i >= n * FP) return;
  int node = i >> 4, c = i & 15;
  float v = (c < F_IN) ? x[(size_t)node * F_IN + c] * dinv[node] : 0.f;
  xs[i] = (bf16)v;
}

// ---------------- CSR build ----------------

__global__ __launch_bounds__(256) void k_scan1(const int* __restrict__ cnt,
                                               int* __restrict__ bsum, int n) {
  __shared__ int sh[256];
  int t = threadIdx.x, i = blockIdx.x * 256 + t;
  sh[t] = (i < n) ? cnt[i] : 0;
  __syncthreads();
  for (int off = 128; off > 0; off >>= 1) {
    if (t < off) sh[t] += sh[t + off];
    __syncthreads();
  }
  if (t == 0) bsum[blockIdx.x] = sh[0];
}

__global__ __launch_bounds__(256) void k_scan2(const int* __restrict__ bsum,
                                               int* __restrict__ boff, int nb) {
  __shared__ int sh[256];
  int t = threadIdx.x;
  int v = (t < nb) ? bsum[t] : 0;
  sh[t] = v;
  __syncthreads();
  for (int off = 1; off < 256; off <<= 1) {
    int x = (t >= off) ? sh[t - off] : 0;
    __syncthreads();
    sh[t] += x;
    __syncthreads();
  }
  if (t < nb) boff[t] = sh[t] - v;
}

__global__ __launch_bounds__(256) void k_scan3(const int* __restrict__ cnt,
                                               const int* __restrict__ boff,
                                               int* __restrict__ rowptr,
                                               int* __restrict__ cur, int n) {
  __shared__ int sh[256];
  int t = threadIdx.x, i = blockIdx.x * 256 + t;
  int v = (i < n) ? cnt[i] : 0;
  sh[t] = v;
  __syncthreads();
  for (int off = 1; off < 256; off <<= 1) {
    int x = (t >= off) ? sh[t - off] : 0;
    __syncthreads();
    sh[t] += x;
    __syncthreads();
  }
  int excl = boff[blockIdx.x] + sh[t] - v;
  if (i < n) {
    rowptr[i] = excl;
    cur[i] = excl;
    if (i == n - 1) rowptr[n] = excl + v;
  }
}

__global__ __launch_bounds__(256) void k_fill(const int* __restrict__ esrc,
                                              const int* __restrict__ edst,
                                              int* __restrict__ cur,
                                              int* __restrict__ cs, int E) {
  int e = blockIdx.x * 256 + threadIdx.x;
  if (e >= E) return;
  int p = atomicAdd(&cur[edst[e]], 1);
  cs[p] = esrc[e];
}

// WT[n][k] = bf16(W[k][n]), 128x128
__global__ __launch_bounds__(256) void k_prepw(const float* __restrict__ W,
                                               bf16* __restrict__ WT) {
  int i = blockIdx.x * 256 + threadIdx.x;  // 16384
  int nn = i >> 7, k = i & 127;
  WT[i] = (bf16)W[k * 128 + nn];
}

// ---------------- gathers (unweighted sums of pre-scaled rows) ----------------

// A1[d] = dinv[d] * (xs[d] + sum xs[src])   [n][16] bf16
__global__ __launch_bounds__(256) void k_gather16(const bf16* __restrict__ xs,
                                                  const float* __restrict__ dinv,
                                                  const int* __restrict__ rowptr,
                                                  const int* __restrict__ cs,
                                                  bf16* __restrict__ A, int n) {
  int t = threadIdx.x;
  int node = blockIdx.x * 16 + (t >> 4);
  int c = t & 15;
  if (node >= n) return;
  float acc = (float)xs[(size_t)node * FP + c];
  int j = rowptr[node], jend = rowptr[node + 1];
  for (; j + 1 < jend; j += 2) {
    int s0 = cs[j], s1 = cs[j + 1];
    acc += (float)xs[(size_t)s0 * FP + c];
    acc += (float)xs[(size_t)s1 * FP + c];
  }
  if (j < jend) acc += (float)xs[(size_t)cs[j] * FP + c];
  A[(size_t)node * FP + c] = (bf16)(acc * dinv[node]);
}

// A[d] = dinv[d] * (hs[d] + sum hs[src])    [n][128] bf16; one wave per node
__global__ __launch_bounds__(256) void k_gather128(const bf16* __restrict__ hs,
                                                   const float* __restrict__ dinv,
                                                   const int* __restrict__ rowptr,
                                                   const int* __restrict__ cs,
                                                   bf16* __restrict__ A, int n) {
  int t = threadIdx.x;
  int node = blockIdx.x * 4 + (t >> 6);
  int l = t & 63;
  if (node >= n) return;
  const unsigned* h2 = (const unsigned*)hs;  // bf16 pair
  unsigned sv = h2[(size_t)node * 64 + l];
  float ax = lo16(sv), ay = hi16(sv);
  int j = rowptr[node], jend = rowptr[node + 1];
  for (; j + 1 < jend; j += 2) {
    int s0 = cs[j], s1 = cs[j + 1];
    unsigned v0 = h2[(size_t)s0 * 64 + l];
    unsigned v1 = h2[(size_t)s1 * 64 + l];
    ax += lo16(v0); ay += hi16(v0);
    ax += lo16(v1); ay += hi16(v1);
  }
  if (j < jend) {
    unsigned v0 = h2[(size_t)cs[j] * 64 + l];
    ax += lo16(v0); ay += hi16(v0);
  }
  float dd = dinv[node];
  bf16* ap = A + (size_t)node * 128 + l * 2;
  ap[0] = (bf16)(ax * dd);
  ap[1] = (bf16)(ay * dd);
}

// ---------------- GEMMs ----------------

// A1[n,16(11 used)] @ W1[11,128] -> relu(+b)*dinv -> hs [n][128] bf16
__global__ __launch_bounds__(256) void k_gemm_in(const bf16* __restrict__ A1,
                                                 const float* __restrict__ W1,
                                                 const float* __restrict__ b1,
                                                 const float* __restrict__ dinv,
                                                 bf16* __restrict__ hs, int n) {
  __shared__ float Ws[F_IN * HID];
  int tid = threadIdx.x;
  for (int i = tid; i < F_IN * HID; i += 256) Ws[i] = W1[i];
  __syncthreads();
  int node = blockIdx.x * 16 + (tid >> 4);
  int cg = tid & 15;
  if (node >= n) return;
  float xr[F_IN];
#pragma unroll
  for (int k = 0; k < F_IN; ++k) xr[k] = (float)A1[(size_t)node * FP + k];
  float acc[8];
#pragma unroll
  for (int j = 0; j < 8; ++j) acc[j] = 0.f;
#pragma unroll
  for (int k = 0; k < F_IN; ++k) {
    const float* wr = &Ws[k * HID + cg * 8];
#pragma unroll
    for (int j = 0; j < 8; ++j) acc[j] = fmaf(xr[k], wr[j], acc[j]);
  }
  float dd = dinv[node];
  bf16* op = hs + (size_t)node * HID + cg * 8;
#pragma unroll
  for (int j = 0; j < 8; ++j)
    op[j] = (bf16)(fmaxf(acc[j] + b1[cg * 8 + j], 0.f) * dd);
}

// A[n,128](bf16) @ WT^T[128,128](bf16) -> relu(+b)[*dinv] -> H [n][128] bf16
// 64 nodes/block, 4 waves x (16 nodes x 128 cols), MFMA 16x16x32.
template <bool SCALE>
__global__ __launch_bounds__(256) void k_gemm_mfma(const bf16* __restrict__ A,
                                                   const bf16* __restrict__ WT,
                                                   const float* __restrict__ b,
                                                   const float* __restrict__ dinv,
                                                   bf16* __restrict__ H, int n) {
  __shared__ bf16 Asm[64 * 128];    // 16KB, XOR-swizzled 16B chunks
  __shared__ bf16 Wsm[128 * 128];   // 32KB, XOR-swizzled 16B chunks
  int tid = threadIdx.x;
  int n0 = blockIdx.x * 64;
  {
    float4* As4 = (float4*)Asm;
#pragma unroll
    for (int it = 0; it < 4; ++it) {
      int i = tid + it * 256;
      int row = i >> 4, kc = i & 15;
      float4 v = make_float4(0.f, 0.f, 0.f, 0.f);
      if (n0 + row < n) v = ((const float4*)(A + (size_t)(n0 + row) * 128))[kc];
      As4[row * 16 + (kc ^ (row & 7))] = v;
    }
    const float4* Wg = (const float4*)WT;
    float4* Ws4 = (float4*)Wsm;
#pragma unroll
    for (int it = 0; it < 8; ++it) {
      int i = tid + it * 256;
      int row = i >> 4, kc = i & 15;
      Ws4[row * 16 + (kc ^ (row & 7))] = Wg[i];
    }
  }
  __syncthreads();
  int lane = tid & 63, wave = tid >> 6;
  int l15 = lane & 15, g = lane >> 4;
  f32x4 acc[8];
#pragma unroll
  for (int f = 0; f < 8; ++f) acc[f] = (f32x4){0.f, 0.f, 0.f, 0.f};
  int arow = wave * 16 + l15;
  const float4* As4 = (const float4*)Asm;
  const float4* Ws4 = (const float4*)Wsm;
#pragma unroll
  for (int kk = 0; kk < 4; ++kk) {
    int kc = kk * 4 + g;
    v8bf a = *(const v8bf*)&As4[arow * 16 + (kc ^ (arow & 7))];
#pragma unroll
    for (int f = 0; f < 8; ++f) {
      int nrow = f * 16 + l15;
      v8bf bf = *(const v8bf*)&Ws4[nrow * 16 + (kc ^ (nrow & 7))];
      acc[f] = __builtin_amdgcn_mfma_f32_16x16x32_bf16(a, bf, acc[f], 0, 0, 0);
    }
  }
  // D layout: col = lane&15 (within frag), row = g*4 + j
  int nodebase = n0 + wave * 16 + g * 4;
  float dv[4];
#pragma unroll
  for (int j = 0; j < 4; ++j)
    dv[j] = (SCALE && nodebase + j < n) ? dinv[nodebase + j] : 1.f;
#pragma unroll
  for (int f = 0; f < 8; ++f) {
    float bias = b[f * 16 + l15];
#pragma unroll
    for (int j = 0; j < 4; ++j) {
      int node = nodebase + j;
      if (node < n) {
        float v = fmaxf(acc[f][j] + bias, 0.f);
        if (SCALE) v *= dv[j];
        H[(size_t)node * 128 + f * 16 + l15] = (bf16)v;
      }
    }
  }
}

// ---------------- pooling + head ----------------

__global__ __launch_bounds__(256) void k_colsum(const bf16* __restrict__ h,
                                                float* __restrict__ gsum, int n) {
  __shared__ float red[256];
  int t = threadIdx.x;
  int f = t & 127;
  int half = t >> 7;
  float s = 0.f;
  for (int node = blockIdx.x * 2 + half; node < n; node += gridDim.x * 2)
    s += (float)h[(size_t)node * HID + f];
  red[t] = s;
  __syncthreads();
  if (t < 128) atomicAdd(&gsum[f], red[t] + red[t + 128]);
}

__global__ __launch_bounds__(128) void k_head(const float* __restrict__ gsum,
    const float* __restrict__ Wv1, const float* __restrict__ bv1,
    const float* __restrict__ Wv2, const float* __restrict__ bv2,
    const float* __restrict__ Wa1, const float* __restrict__ ba1,
    const float* __restrict__ Wa2, const float* __restrict__ ba2,
    float* __restrict__ out, int n) {
  __shared__ float gs[HID], ha[HID], red[2], advs[N_ACT], vsh;
  int t = threadIdx.x;
  gs[t] = gsum[t] * (1.0f / (float)n);
  __syncthreads();
  float av = bv1[t], aa = ba1[t];
  for (int k = 0; k < HID; ++k) {
    float gk = gs[k];
    av = fmaf(gk, Wv1[k * HID + t], av);
    aa = fmaf(gk, Wa1[k * HID + t], aa);
  }
  float hv = fmaxf(av, 0.f);
  ha[t] = fmaxf(aa, 0.f);
  float pv = hv * Wv2[t];
#pragma unroll
  for (int o = 32; o > 0; o >>= 1) pv += __shfl_down(pv, o);
  if ((t & 63) == 0) red[t >> 6] = pv;
  __syncthreads();
  if (t == 0) vsh = red[0] + red[1] + bv2[0];
  if (t < N_ACT) {
    float adv = ba2[t];
    for (int j = 0; j < HID; ++j) adv = fmaf(ha[j], Wa2[j * N_ACT + t], adv);
    advs[t] = adv;
  }
  __syncthreads();
  if (t < N_ACT) {
    float m = 0.f;
#pragma unroll
    for (int a = 0; a < N_ACT; ++a) m += advs[a];
    m *= (1.0f / N_ACT);
    out[t] = vsh + advs[t] - m;
  }
}

// ---------------- launch ----------------

extern "C" void kernel_launch(void* const* d_in, const int* in_sizes, int n_in,
                              void* d_out, int out_size, void* d_ws, size_t ws_size,
                              hipStream_t stream) {
  const float* x   = (const float*)d_in[0];
  const int*   ei  = (const int*)d_in[1];
  const float* W1  = (const float*)d_in[2];
  const float* b1  = (const float*)d_in[3];
  const float* W2  = (const float*)d_in[4];
  const float* b2  = (const float*)d_in[5];
  const float* W3  = (const float*)d_in[6];
  const float* b3  = (const float*)d_in[7];
  const float* Wv1 = (const float*)d_in[8];
  const float* bv1 = (const float*)d_in[9];
  const float* Wv2 = (const float*)d_in[10];
  const float* bv2 = (const float*)d_in[11];
  const float* Wa1 = (const float*)d_in[12];
  const float* ba1 = (const float*)d_in[13];
  const float* Wa2 = (const float*)d_in[14];
  const float* ba2 = (const float*)d_in[15];
  float* out = (float*)d_out;

  const int N = in_sizes[0] / F_IN;   // 50000
  const int E = in_sizes[1] / 2;      // 800000
  const int* esrc = ei;
  const int* edst = ei + E;
  const int nb = (N + 255) / 256;

  char* p = (char*)d_ws;
  auto alloc = [&](size_t bytes) {
    void* r = (void*)p;
    p += (bytes + 1023) & ~(size_t)1023;
    return r;
  };
  int*   cnt    = (int*)alloc((size_t)N * 4);
  float* dinv   = (float*)alloc((size_t)N * 4);
  int*   rowptr = (int*)alloc((size_t)(N + 1) * 4);
  int*   cur    = (int*)alloc((size_t)N * 4);
  int*   bsum   = (int*)alloc(256 * 4);
  int*   boff   = (int*)alloc(256 * 4);
  int*   cs     = (int*)alloc((size_t)E * 4);
  bf16*  xs     = (bf16*)alloc((size_t)N * FP * 2);
  bf16*  A1     = (bf16*)alloc((size_t)N * FP * 2);
  bf16*  WT2    = (bf16*)alloc(128 * 128 * 2);
  bf16*  WT3    = (bf16*)alloc(128 * 128 * 2);
  bf16*  HB     = (bf16*)alloc((size_t)N * HID * 2);
  bf16*  AB     = (bf16*)alloc((size_t)N * HID * 2);
  float* gsum   = (float*)alloc(HID * 4);

  hipMemsetAsync(cnt, 0, (size_t)N * 4, stream);
  hipMemsetAsync(gsum, 0, HID * 4, stream);

  k_count_deg<<<(E + 255) / 256, 256, 0, stream>>>(edst, cnt, E);
  k_dinv<<<nb, 256, 0, stream>>>(cnt, dinv, N);
  k_pad<<<(N * FP + 255) / 256, 256, 0, stream>>>(x, dinv, xs, N);
  k_scan1<<<nb, 256, 0, stream>>>(cnt, bsum, N);
  k_scan2<<<1, 256, 0, stream>>>(bsum, boff, nb);
  k_scan3<<<nb, 256, 0, stream>>>(cnt, boff, rowptr, cur, N);
  k_fill<<<(E + 255) / 256, 256, 0, stream>>>(esrc, edst, cur, cs, E);
  k_prepw<<<64, 256, 0, stream>>>(W2, WT2);
  k_prepw<<<64, 256, 0, stream>>>(W3, WT3);

  // layer 1
  k_gather16<<<(N + 15) / 16, 256, 0, stream>>>(xs, dinv, rowptr, cs, A1, N);
  k_gemm_in<<<(N + 15) / 16, 256, 0, stream>>>(A1, W1, b1, dinv, HB, N);

  // layer 2
  k_gather128<<<(N + 3) / 4, 256, 0, stream>>>(HB, dinv, rowptr, cs, AB, N);
  k_gemm_mfma<true><<<(N + 63) / 64, 256, 0, stream>>>(AB, WT2, b2, dinv, HB, N);

  // layer 3
  k_gather128<<<(N + 3) / 4, 256, 0, stream>>>(HB, dinv, rowptr, cs, AB, N);
  k_gemm_mfma<false><<<(N + 63) / 64, 256, 0, stream>>>(AB, WT3, b3, dinv, HB, N);

  // pool + head
  k_colsum<<<512, 256, 0, stream>>>(HB, gsum, N);
  k_head<<<1, 128, 0, stream>>>(gsum, Wv1, bv1, Wv2, bv2, Wa1, ba1, Wa2, ba2, out, N);
}